// Round 4
// baseline (120.704 us; speedup 1.0000x reference)
//
#include <hip/hip_runtime.h>
#include <hip/hip_bf16.h>

// SpecAugment: out = (x + noise*0.04) masked by per-sample freq/time zero masks.
// x, noise: [B=128, C=3, F=128, T=1000] f32. f0/f_len: [B,2], t0/t_len: [B,2] i32.
// Memory-bound / latency-limited. Grid-stride with EXACT trip count:
// 1920 blocks x 256 thr = 491520 threads; NV4 = 12,288,000 = 491520 * 25
// -> 25 iters/thread, no bounds check, unroll 5 for deep MLP.
// Normal stores (R3 showed nontemporal stores REGRESS on gfx950).

#define B 128
#define C 3
#define Fd 128
#define T 1000
#define NOISE_STD 0.04f

typedef float  f32x4 __attribute__((ext_vector_type(4)));
typedef int    i32x2 __attribute__((ext_vector_type(2)));

constexpr int ROWS       = B * C * Fd;        // 49152
constexpr int V4_PER_ROW = T / 4;             // 250
constexpr int NV4        = ROWS * V4_PER_ROW; // 12,288,000 float4s
constexpr int NBLOCKS    = 1920;
constexpr int NTHREADS   = NBLOCKS * 256;     // 491,520
constexpr int ITERS      = NV4 / NTHREADS;    // 25 exactly

__global__ __launch_bounds__(256) void specaug_kernel(
    const float* __restrict__ x, const float* __restrict__ noise,
    const int* __restrict__ f0, const int* __restrict__ f_len,
    const int* __restrict__ t0, const int* __restrict__ t_len,
    float* __restrict__ out)
{
    const int gid = blockIdx.x * blockDim.x + threadIdx.x;

#pragma unroll 5
    for (int it = 0; it < ITERS; ++it) {
        const int i = gid + it * NTHREADS;
        const unsigned row = (unsigned)i / (unsigned)V4_PER_ROW;   // magic-mul
        const int rem = i - (int)row * V4_PER_ROW;
        const int b   = (int)(row / (unsigned)(C * Fd));
        const int f   = (int)(row & (Fd - 1));                     // row % 128

        const i32x2 fa = reinterpret_cast<const i32x2*>(f0)[b];
        const i32x2 fl = reinterpret_cast<const i32x2*>(f_len)[b];
        const bool fmask = (f >= fa.x && f < fa.x + fl.x) ||
                           (f >= fa.y && f < fa.y + fl.y);

        f32x4* outp = reinterpret_cast<f32x4*>(out) + i;

        if (fmask) {
            // Whole row zeroed — skip both input reads.
            f32x4 z = {0.f, 0.f, 0.f, 0.f};
            *outp = z;
            continue;
        }

        const i32x2 ta = reinterpret_cast<const i32x2*>(t0)[b];
        const i32x2 tl = reinterpret_cast<const i32x2*>(t_len)[b];

        const f32x4 xv = reinterpret_cast<const f32x4*>(x)[i];
        const f32x4 nv = reinterpret_cast<const f32x4*>(noise)[i];

        const int t = rem * 4;
        f32x4 ov;
#pragma unroll
        for (int k = 0; k < 4; ++k) {
            const int tt = t + k;
            const bool tmask = (tt >= ta.x && tt < ta.x + tl.x) ||
                               (tt >= ta.y && tt < ta.y + tl.y);
            ov[k] = tmask ? 0.f : fmaf(nv[k], NOISE_STD, xv[k]);
        }
        *outp = ov;
    }
}

extern "C" void kernel_launch(void* const* d_in, const int* in_sizes, int n_in,
                              void* d_out, int out_size, void* d_ws, size_t ws_size,
                              hipStream_t stream)
{
    const float* x     = (const float*)d_in[0];
    const float* noise = (const float*)d_in[1];
    const int*   f0    = (const int*)d_in[2];
    const int*   f_len = (const int*)d_in[3];
    const int*   t0    = (const int*)d_in[4];
    const int*   t_len = (const int*)d_in[5];
    float* out = (float*)d_out;

    specaug_kernel<<<NBLOCKS, 256, 0, stream>>>(x, noise, f0, f_len, t0, t_len, out);
}

// Round 5
// 108.581 us; speedup vs baseline: 1.1116x; 1.1116x over previous
//
#include <hip/hip_runtime.h>
#include <hip/hip_bf16.h>

// SpecAugment: out = (x + noise*0.04) masked by per-sample freq/time zero masks.
// x, noise: [B=128, C=3, F=128, T=1000] f32. f0/f_len: [B,2], t0/t_len: [B,2] i32.
// Memory-bound / latency-limited. R4 lesson: grid-stride regresses vs
// block-contiguous. Structure: one block per 4 CONSECUTIVE rows (4|Fd so all
// share b,c). 250 active threads; each thread does float4 #tid of all 4 rows:
// 8 independent loads in flight, tmask computed once, fmask block-uniform.

#define B 128
#define C 3
#define Fd 128
#define T 1000
#define NOISE_STD 0.04f

typedef float  f32x4 __attribute__((ext_vector_type(4)));
typedef int    i32x2 __attribute__((ext_vector_type(2)));

constexpr int ROWS        = B * C * Fd;   // 49152
constexpr int V4_PER_ROW  = T / 4;        // 250
constexpr int ROWS_PER_WG = 4;
constexpr int NBLOCKS     = ROWS / ROWS_PER_WG;  // 12288

__global__ __launch_bounds__(256) void specaug_kernel(
    const float* __restrict__ x, const float* __restrict__ noise,
    const int* __restrict__ f0, const int* __restrict__ f_len,
    const int* __restrict__ t0, const int* __restrict__ t_len,
    float* __restrict__ out)
{
    const int tid = threadIdx.x;
    if (tid >= V4_PER_ROW) return;                 // 250 active

    const int r0 = blockIdx.x * ROWS_PER_WG;       // first row of this block
    const int b  = r0 / (C * Fd);
    const int fb = r0 & (Fd - 1);                  // freq index of row 0

    const i32x2 fa = reinterpret_cast<const i32x2*>(f0)[b];
    const i32x2 fl = reinterpret_cast<const i32x2*>(f_len)[b];
    const i32x2 ta = reinterpret_cast<const i32x2*>(t0)[b];
    const i32x2 tl = reinterpret_cast<const i32x2*>(t_len)[b];

    // Block-uniform freq masks for the 4 rows.
    bool fm[ROWS_PER_WG];
#pragma unroll
    for (int j = 0; j < ROWS_PER_WG; ++j) {
        const int f = fb + j;
        fm[j] = (f >= fa.x && f < fa.x + fl.x) || (f >= fa.y && f < fa.y + fl.y);
    }

    // Time mask — same t for all 4 rows, compute once.
    const int t = tid * 4;
    bool tm[4];
#pragma unroll
    for (int k = 0; k < 4; ++k) {
        const int tt = t + k;
        tm[k] = (tt >= ta.x && tt < ta.x + tl.x) || (tt >= ta.y && tt < ta.y + tl.y);
    }

    const long long base = (long long)r0 * V4_PER_ROW + tid;  // float4 index
    const f32x4* xp = reinterpret_cast<const f32x4*>(x) + base;
    const f32x4* np = reinterpret_cast<const f32x4*>(noise) + base;
    f32x4*       op = reinterpret_cast<f32x4*>(out) + base;

    // Issue all loads first for maximum MLP (uniform branches — no divergence).
    f32x4 xv[ROWS_PER_WG], nv[ROWS_PER_WG];
#pragma unroll
    for (int j = 0; j < ROWS_PER_WG; ++j) {
        if (!fm[j]) {
            xv[j] = xp[j * V4_PER_ROW];
            nv[j] = np[j * V4_PER_ROW];
        }
    }

#pragma unroll
    for (int j = 0; j < ROWS_PER_WG; ++j) {
        f32x4 ov;
        if (fm[j]) {
            ov = (f32x4){0.f, 0.f, 0.f, 0.f};
        } else {
#pragma unroll
            for (int k = 0; k < 4; ++k)
                ov[k] = tm[k] ? 0.f : fmaf(nv[j][k], NOISE_STD, xv[j][k]);
        }
        op[j * V4_PER_ROW] = ov;
    }
}

extern "C" void kernel_launch(void* const* d_in, const int* in_sizes, int n_in,
                              void* d_out, int out_size, void* d_ws, size_t ws_size,
                              hipStream_t stream)
{
    const float* x     = (const float*)d_in[0];
    const float* noise = (const float*)d_in[1];
    const int*   f0    = (const int*)d_in[2];
    const int*   f_len = (const int*)d_in[3];
    const int*   t0    = (const int*)d_in[4];
    const int*   t_len = (const int*)d_in[5];
    float* out = (float*)d_out;

    specaug_kernel<<<NBLOCKS, 256, 0, stream>>>(x, noise, f0, f_len, t0, t_len, out);
}

// Round 6
// 106.956 us; speedup vs baseline: 1.1285x; 1.0152x over previous
//
#include <hip/hip_runtime.h>
#include <hip/hip_bf16.h>

// SpecAugment: out = (x + noise*0.04) masked by per-sample freq/time zero masks.
// x, noise: [B=128, C=3, F=128, T=1000] f32. f0/f_len: [B,2], t0/t_len: [B,2] i32.
// Memory-bound. Empirical structure ranking (R1/R5/R4): one block per row
// (49152 small blocks) beats multi-row blocks and grid-stride. This round:
// R1 structure + NON-TEMPORAL stores (R3-vs-R4 isolated nt as +5us on the
// same structure: write-once output stays out of the cache path serving the
// re-read inputs).

#define B 128
#define C 3
#define Fd 128
#define T 1000
#define NOISE_STD 0.04f

typedef float  f32x4 __attribute__((ext_vector_type(4)));
typedef int    i32x2 __attribute__((ext_vector_type(2)));

constexpr int ROWS       = B * C * Fd;   // 49152
constexpr int V4_PER_ROW = T / 4;        // 250

__global__ __launch_bounds__(256) void specaug_kernel(
    const float* __restrict__ x, const float* __restrict__ noise,
    const int* __restrict__ f0, const int* __restrict__ f_len,
    const int* __restrict__ t0, const int* __restrict__ t_len,
    float* __restrict__ out)
{
    const int row = blockIdx.x;              // [0, B*C*Fd)
    const int f   = row & (Fd - 1);          // row % 128
    const int b   = row / (C * Fd);
    const int tid = threadIdx.x;             // 0..255; 250 active

    if (tid >= V4_PER_ROW) return;

    const i32x2 fa = reinterpret_cast<const i32x2*>(f0)[b];
    const i32x2 fl = reinterpret_cast<const i32x2*>(f_len)[b];
    const bool fmask = (f >= fa.x && f < fa.x + fl.x) ||
                       (f >= fa.y && f < fa.y + fl.y);

    const long long base = (long long)row * V4_PER_ROW + tid;  // float4 index
    f32x4* outp = reinterpret_cast<f32x4*>(out) + base;

    if (fmask) {
        // Whole row zeroed — skip both input reads.
        f32x4 z = {0.f, 0.f, 0.f, 0.f};
        __builtin_nontemporal_store(z, outp);
        return;
    }

    const i32x2 ta = reinterpret_cast<const i32x2*>(t0)[b];
    const i32x2 tl = reinterpret_cast<const i32x2*>(t_len)[b];

    const f32x4 xv = reinterpret_cast<const f32x4*>(x)[base];
    const f32x4 nv = reinterpret_cast<const f32x4*>(noise)[base];

    const int t = tid * 4;
    f32x4 ov;
#pragma unroll
    for (int k = 0; k < 4; ++k) {
        const int tt = t + k;
        const bool tmask = (tt >= ta.x && tt < ta.x + tl.x) ||
                           (tt >= ta.y && tt < ta.y + tl.y);
        ov[k] = tmask ? 0.f : fmaf(nv[k], NOISE_STD, xv[k]);
    }
    __builtin_nontemporal_store(ov, outp);
}

extern "C" void kernel_launch(void* const* d_in, const int* in_sizes, int n_in,
                              void* d_out, int out_size, void* d_ws, size_t ws_size,
                              hipStream_t stream)
{
    const float* x     = (const float*)d_in[0];
    const float* noise = (const float*)d_in[1];
    const int*   f0    = (const int*)d_in[2];
    const int*   f_len = (const int*)d_in[3];
    const int*   t0    = (const int*)d_in[4];
    const int*   t_len = (const int*)d_in[5];
    float* out = (float*)d_out;

    specaug_kernel<<<ROWS, 256, 0, stream>>>(x, noise, f0, f_len, t0, t_len, out);
}